// Round 1
// baseline (604.483 us; speedup 1.0000x reference)
//
#include <hip/hip_runtime.h>

// Problem constants (from reference setup_inputs): image (C,H,W) fp32, flow (2,H,W) fp32.
constexpr int C = 32;
constexpr int H = 1024;
constexpr int W = 2048;
constexpr int HW = H * W;

__global__ __launch_bounds__(256) void warp_kernel(
    const float* __restrict__ image,
    const float* __restrict__ flow,
    float* __restrict__ out)
{
    const int idx = blockIdx.x * blockDim.x + threadIdx.x;
    if (idx >= HW) return;

    const int x = idx & (W - 1);   // W = 2048, power of 2
    const int y = idx >> 11;       // log2(W) = 11

    // flow[0] = u-displacement, flow[1] = v-displacement
    const float u = (float)x + flow[idx];
    const float v = (float)y + flow[HW + idx];

    const float u0f = floorf(u);
    const float v0f = floorf(v);
    const float wu = u - u0f;
    const float wv = v - v0f;

    const int u0 = (int)u0f;
    const int v0 = (int)v0f;
    const int u1 = u0 + 1;
    const int v1 = v0 + 1;

    const bool vu0 = (u0 >= 0) & (u0 <= W - 1);
    const bool vu1 = (u1 >= 0) & (u1 <= W - 1);
    const bool vv0 = (v0 >= 0) & (v0 <= H - 1);
    const bool vv1 = (v1 >= 0) & (v1 <= H - 1);

    const int u0c = min(max(u0, 0), W - 1);
    const int u1c = min(max(u1, 0), W - 1);
    const int v0c = min(max(v0, 0), H - 1);
    const int v1c = min(max(v1, 0), H - 1);

    // Fold per-corner validity into the weights: w * where(valid, g, 0)
    // == (valid ? w : 0) * g_clamped   (all values finite).
    float w00 = (1.0f - wu) * (1.0f - wv);
    float w10 = wu * (1.0f - wv);
    float w01 = (1.0f - wu) * wv;
    float w11 = wu * wv;
    w00 = (vv0 & vu0) ? w00 : 0.0f;
    w10 = (vv0 & vu1) ? w10 : 0.0f;
    w01 = (vv1 & vu0) ? w01 : 0.0f;
    w11 = (vv1 & vu1) ? w11 : 0.0f;

    const int off00 = v0c * W + u0c;
    const int off10 = v0c * W + u1c;
    const int off01 = v1c * W + u0c;
    const int off11 = v1c * W + u1c;

    const float* __restrict__ img = image;
    float* __restrict__ o = out + idx;

    #pragma unroll
    for (int c = 0; c < C; ++c) {
        const float g00 = img[off00];
        const float g10 = img[off10];
        const float g01 = img[off01];
        const float g11 = img[off11];
        o[(size_t)c * HW] = w00 * g00 + w10 * g10 + w01 * g01 + w11 * g11;
        img += HW;
    }
}

extern "C" void kernel_launch(void* const* d_in, const int* in_sizes, int n_in,
                              void* d_out, int out_size, void* d_ws, size_t ws_size,
                              hipStream_t stream) {
    const float* image = (const float*)d_in[0];
    const float* flow  = (const float*)d_in[1];
    float* out = (float*)d_out;

    const int threads = 256;
    const int blocks = (HW + threads - 1) / threads;  // 8192 blocks
    warp_kernel<<<blocks, threads, 0, stream>>>(image, flow, out);
}

// Round 2
// 599.112 us; speedup vs baseline: 1.0090x; 1.0090x over previous
//
#include <hip/hip_runtime.h>

// Problem constants: image (C,H,W) fp32, flow (2,H,W) fp32.
constexpr int C = 32;
constexpr int H = 1024;
constexpr int W = 2048;
constexpr int HW = H * W;
constexpr int CG = 8;           // channels per load batch (32 loads in flight)

__global__ void warp_kernel(
    const float* __restrict__ image,
    const float* __restrict__ flow,
    float* __restrict__ out)
{
    const int idx = blockIdx.x * blockDim.x + threadIdx.x;

    const int x = idx & (W - 1);   // W = 2048
    const int y = idx >> 11;       // log2(W)

    const float u = (float)x + flow[idx];
    const float v = (float)y + flow[HW + idx];

    const float u0f = floorf(u);
    const float v0f = floorf(v);
    const float wu = u - u0f;
    const float wv = v - v0f;

    const int u0 = (int)u0f;
    const int v0 = (int)v0f;
    const int u1 = u0 + 1;
    const int v1 = v0 + 1;

    const bool vu0 = (u0 >= 0) & (u0 <= W - 1);
    const bool vu1 = (u1 >= 0) & (u1 <= W - 1);
    const bool vv0 = (v0 >= 0) & (v0 <= H - 1);
    const bool vv1 = (v1 >= 0) & (v1 <= H - 1);

    const int u0c = min(max(u0, 0), W - 1);
    const int u1c = min(max(u1, 0), W - 1);
    const int v0c = min(max(v0, 0), H - 1);
    const int v1c = min(max(v1, 0), H - 1);

    // Fold validity into weights: w * where(valid, g, 0) == (valid?w:0) * g_clamped.
    float w00 = (1.0f - wu) * (1.0f - wv);
    float w10 = wu * (1.0f - wv);
    float w01 = (1.0f - wu) * wv;
    float w11 = wu * wv;
    w00 = (vv0 & vu0) ? w00 : 0.0f;
    w10 = (vv0 & vu1) ? w10 : 0.0f;
    w01 = (vv1 & vu0) ? w01 : 0.0f;
    w11 = (vv1 & vu1) ? w11 : 0.0f;

    const int off00 = v0c * W + u0c;
    const int off10 = v0c * W + u1c;
    const int off01 = v1c * W + u0c;
    const int off11 = v1c * W + u1c;

    #pragma unroll
    for (int g = 0; g < C / CG; ++g) {
        const float* __restrict__ img = image + (size_t)(g * CG) * HW;

        float g00[CG], g10[CG], g01[CG], g11[CG];
        // Batch: issue all 4*CG independent gathers before any use,
        // so the wave keeps ~32 loads in flight (MLP >> occupancy-TLP).
        #pragma unroll
        for (int c = 0; c < CG; ++c) {
            const size_t base = (size_t)c * HW;
            g00[c] = img[base + off00];
            g10[c] = img[base + off10];
            g01[c] = img[base + off01];
            g11[c] = img[base + off11];
        }
        #pragma unroll
        for (int c = 0; c < CG; ++c) {
            out[(size_t)(g * CG + c) * HW + idx] =
                w00 * g00[c] + w10 * g10[c] + w01 * g01[c] + w11 * g11[c];
        }
    }
}

extern "C" void kernel_launch(void* const* d_in, const int* in_sizes, int n_in,
                              void* d_out, int out_size, void* d_ws, size_t ws_size,
                              hipStream_t stream) {
    const float* image = (const float*)d_in[0];
    const float* flow  = (const float*)d_in[1];
    float* out = (float*)d_out;

    const int threads = 256;
    const int blocks = HW / threads;  // 8192 blocks, exact cover
    warp_kernel<<<blocks, threads, 0, stream>>>(image, flow, out);
}

// Round 3
// 583.138 us; speedup vs baseline: 1.0366x; 1.0274x over previous
//
#include <hip/hip_runtime.h>
#include <cstring>

// Problem constants: image (C,H,W) fp32, flow (2,H,W) fp32.
constexpr int C = 32;
constexpr int H = 1024;
constexpr int W = 2048;
constexpr int HW = H * W;
constexpr int CG = 16;          // channels per load batch -> 2*CG = 32 loads in flight

__global__ __attribute__((amdgpu_waves_per_eu(2))) void warp_kernel(
    const float* __restrict__ image,
    const float* __restrict__ flow,
    float* __restrict__ out)
{
    const int idx = blockIdx.x * blockDim.x + threadIdx.x;

    const int x = idx & (W - 1);   // W = 2048
    const int y = idx >> 11;       // log2(W)

    const float u = (float)x + flow[idx];
    const float v = (float)y + flow[HW + idx];

    const float u0f = floorf(u);
    const float v0f = floorf(v);
    const float wu = u - u0f;
    const float wv = v - v0f;

    const int u0 = (int)u0f;
    const int v0 = (int)v0f;
    const int u1 = u0 + 1;
    const int v1 = v0 + 1;

    const bool vu0 = (u0 >= 0) & (u0 <= W - 1);
    const bool vu1 = (u1 >= 0) & (u1 <= W - 1);
    const bool vv0 = (v0 >= 0) & (v0 <= H - 1);
    const bool vv1 = (v1 >= 0) & (v1 <= H - 1);

    const int v0c = min(max(v0, 0), H - 1);
    const int v1c = min(max(v1, 0), H - 1);

    // Column pair base: load image[row][base_u .. base_u+1] as one 8B load.
    // iu0/iu1 select which half holds the (clamped) u0c/u1c column.
    // Invalid corners have weight 0, so any in-bounds value is acceptable.
    const int base_u = min(max(u0, 0), W - 2);
    const int u0c = min(max(u0, 0), W - 1);
    const int u1c = min(max(u1, 0), W - 1);
    const int iu0 = u0c - base_u;   // 0 or 1
    const int iu1 = u1c - base_u;   // 0 or 1

    // Fold validity into weights.
    float w00 = (1.0f - wu) * (1.0f - wv);
    float w10 = wu * (1.0f - wv);
    float w01 = (1.0f - wu) * wv;
    float w11 = wu * wv;
    w00 = (vv0 & vu0) ? w00 : 0.0f;
    w10 = (vv0 & vu1) ? w10 : 0.0f;
    w01 = (vv1 & vu0) ? w01 : 0.0f;
    w11 = (vv1 & vu1) ? w11 : 0.0f;

    const int off0 = v0c * W + base_u;   // top row pair
    const int off1 = v1c * W + base_u;   // bottom row pair

    #pragma unroll
    for (int g = 0; g < C / CG; ++g) {
        const float* __restrict__ img = image + (size_t)(g * CG) * HW;

        float2 p0[CG], p1[CG];
        // Issue all 2*CG independent 8B gathers before any use -> deep MLP.
        #pragma unroll
        for (int c = 0; c < CG; ++c) {
            const size_t base = (size_t)c * HW;
            __builtin_memcpy(&p0[c], img + base + off0, 8);
            __builtin_memcpy(&p1[c], img + base + off1, 8);
        }
        #pragma unroll
        for (int c = 0; c < CG; ++c) {
            const float g00 = iu0 ? p0[c].y : p0[c].x;
            const float g10 = iu1 ? p0[c].y : p0[c].x;
            const float g01 = iu0 ? p1[c].y : p1[c].x;
            const float g11 = iu1 ? p1[c].y : p1[c].x;
            const float val = w00 * g00 + w10 * g10 + w01 * g01 + w11 * g11;
            // Output is never re-read: keep it out of L2 so gathers stay hot.
            __builtin_nontemporal_store(val, &out[(size_t)(g * CG + c) * HW + idx]);
        }
    }
}

extern "C" void kernel_launch(void* const* d_in, const int* in_sizes, int n_in,
                              void* d_out, int out_size, void* d_ws, size_t ws_size,
                              hipStream_t stream) {
    const float* image = (const float*)d_in[0];
    const float* flow  = (const float*)d_in[1];
    float* out = (float*)d_out;

    const int threads = 256;
    const int blocks = HW / threads;  // 8192 blocks, exact cover
    warp_kernel<<<blocks, threads, 0, stream>>>(image, flow, out);
}

// Round 4
// 552.394 us; speedup vs baseline: 1.0943x; 1.0557x over previous
//
#include <hip/hip_runtime.h>

// Problem constants: image (C,H,W) fp32, flow (2,H,W) fp32.
constexpr int C  = 32;
constexpr int H  = 1024;
constexpr int W  = 2048;
constexpr int HW = H * W;

constexpr int TW = 64;              // tile width  (pixels)
constexpr int TH = 32;              // tile height (pixels)
constexpr int MC = 8;               // col margin each side
constexpr int MR = 6;               // row margin each side
constexpr int SC = TW + 2 * MC;     // 80 staged cols
constexpr int SR = TH + 2 * MR;     // 44 staged rows
constexpr int SLOTS = SR * (SC / 4);// 880 float4 staging slots
constexpr int NPX = (TW * TH) / 256;// 8 pixels per thread

__global__ __launch_bounds__(256) void warp_kernel(
    const float* __restrict__ image,
    const float* __restrict__ flow,
    float* __restrict__ out)
{
    __shared__ float lsbuf[2][SR * SC];   // 2 x 14080 B = 28160 B

    const int tid = threadIdx.x;
    const int tx0 = blockIdx.x * TW;
    const int ty0 = blockIdx.y * TH;

    // ---- staging slot address precompute (channel-invariant) ----
    // slot s -> staged row r = s/20, col group c4 = (s%20)*4
    int s_srowW[4], s_scol[4], s_lds[4];
    bool s_colok[4];
    #pragma unroll
    for (int k = 0; k < 4; ++k) {
        const int s = tid + 256 * k;
        if (s < SLOTS) {
            const int r   = s / (SC / 4);
            const int c4  = (s - r * (SC / 4)) * 4;
            const int srow = min(max(ty0 - MR + r, 0), H - 1); // row clamp
            const int scol = tx0 - MC + c4;
            s_srowW[k] = srow * W;
            s_scol[k]  = scol;
            s_lds[k]   = r * SC + c4;
            s_colok[k] = (scol >= 0) && (scol + 3 < W);
        } else {
            s_srowW[k] = -1;  // only possible for k==3 (tid >= 112)
        }
    }

    auto stage_load = [&](int c, float4* vals) {
        const float* __restrict__ imgc = image + (size_t)c * HW;
        #pragma unroll
        for (int k = 0; k < 4; ++k) {
            if (k == 3 && s_srowW[3] < 0) continue;
            if (s_colok[k]) {
                vals[k] = *(const float4*)(imgc + s_srowW[k] + s_scol[k]);
            } else {   // edge-column tiles: per-element clamped gather
                float4 t;
                t.x = imgc[s_srowW[k] + min(max(s_scol[k] + 0, 0), W - 1)];
                t.y = imgc[s_srowW[k] + min(max(s_scol[k] + 1, 0), W - 1)];
                t.z = imgc[s_srowW[k] + min(max(s_scol[k] + 2, 0), W - 1)];
                t.w = imgc[s_srowW[k] + min(max(s_scol[k] + 3, 0), W - 1)];
                vals[k] = t;
            }
        }
    };
    auto stage_write = [&](int b, const float4* vals) {
        #pragma unroll
        for (int k = 0; k < 4; ++k) {
            if (k == 3 && s_srowW[3] < 0) continue;
            *(float4*)&lsbuf[b][s_lds[k]] = vals[k];
        }
    };

    // ---- per-pixel precompute (channel-invariant): weights + LDS addr ----
    const int tx  = tid & (TW - 1);
    const int tyq = tid >> 6;                 // 0..3
    const int xpx = tx0 + tx;
    const int po0 = (ty0 + tyq) * W + xpx;    // pixel flat offset, row stride 4*W per i

    float w00[NPX], w10[NPX], w01[NPX], w11[NPX];
    int addr0[NPX];
    unsigned fmask = 0;

    #pragma unroll
    for (int i = 0; i < NPX; ++i) {
        const int po  = po0 + i * 4 * W;
        const int ypx = ty0 + tyq + 4 * i;
        const float u = (float)xpx + flow[po];
        const float v = (float)ypx + flow[HW + po];
        const float u0f = floorf(u);
        const float v0f = floorf(v);
        const float wu = u - u0f;
        const float wv = v - v0f;
        const int u0 = (int)u0f;
        const int v0 = (int)v0f;

        const bool vu0 = (u0 >= 0) & (u0 <= W - 1);
        const bool vu1 = (u0 + 1 >= 0) & (u0 + 1 <= W - 1);
        const bool vv0 = (v0 >= 0) & (v0 <= H - 1);
        const bool vv1 = (v0 + 1 >= 0) & (v0 + 1 <= H - 1);

        // Fold validity into weights: w * where(valid,g,0) == (valid?w:0)*g_clamped.
        float a = (1.0f - wu) * (1.0f - wv);
        float b = wu * (1.0f - wv);
        float c = (1.0f - wu) * wv;
        float d = wu * wv;
        w00[i] = (vv0 & vu0) ? a : 0.0f;
        w10[i] = (vv0 & vu1) ? b : 0.0f;
        w01[i] = (vv1 & vu0) ? c : 0.0f;
        w11[i] = (vv1 & vu1) ? d : 0.0f;

        // Fast path iff the 2x2 footprint lies inside the staged window.
        const bool fast = (u0 >= tx0 - MC) & (u0 <= tx0 + TW + MC - 2) &
                          (v0 >= ty0 - MR) & (v0 <= ty0 + TH + MR - 2);
        fmask |= (fast ? 1u : 0u) << i;
        addr0[i] = (v0 - ty0 + MR) * SC + (u0 - tx0 + MC);
    }

    // ---- channel loop: double-buffered staging, one barrier per channel ----
    float4 vals[4];
    stage_load(0, vals);
    stage_write(0, vals);
    __syncthreads();

    for (int c = 0; c < C; ++c) {
        if (c + 1 < C) stage_load(c + 1, vals);   // loads in flight over compute

        const float* __restrict__ ls = lsbuf[c & 1];
        const float* __restrict__ imgc = image + (size_t)c * HW;
        float* __restrict__ outc = out + (size_t)c * HW;

        #pragma unroll
        for (int i = 0; i < NPX; ++i) {
            const int po = po0 + i * 4 * W;
            float r;
            if ((fmask >> i) & 1u) {
                const int a0 = addr0[i];
                const float g00 = ls[a0];
                const float g10 = ls[a0 + 1];
                const float g01 = ls[a0 + SC];
                const float g11 = ls[a0 + SC + 1];
                r = w00[i] * g00 + w10[i] * g10 + w01[i] * g01 + w11[i] * g11;
            } else {
                // Rare outlier (|flow| beyond margin): global clamped fallback.
                const int ypx = ty0 + tyq + 4 * i;
                const float u = (float)xpx + flow[po];
                const float v = (float)ypx + flow[HW + po];
                const int u0 = (int)floorf(u);
                const int v0 = (int)floorf(v);
                const int u0c = min(max(u0, 0), W - 1);
                const int u1c = min(max(u0 + 1, 0), W - 1);
                const int v0c = min(max(v0, 0), H - 1);
                const int v1c = min(max(v0 + 1, 0), H - 1);
                r = w00[i] * imgc[v0c * W + u0c] + w10[i] * imgc[v0c * W + u1c]
                  + w01[i] * imgc[v1c * W + u0c] + w11[i] * imgc[v1c * W + u1c];
            }
            // Output is never re-read: keep it from evicting image lines.
            __builtin_nontemporal_store(r, &outc[po]);
        }

        if (c + 1 < C) {
            stage_write((c + 1) & 1, vals);
            __syncthreads();
        }
    }
}

extern "C" void kernel_launch(void* const* d_in, const int* in_sizes, int n_in,
                              void* d_out, int out_size, void* d_ws, size_t ws_size,
                              hipStream_t stream) {
    const float* image = (const float*)d_in[0];
    const float* flow  = (const float*)d_in[1];
    float* out = (float*)d_out;

    dim3 grid(W / TW, H / TH);   // 32 x 32 = 1024 blocks
    warp_kernel<<<grid, 256, 0, stream>>>(image, flow, out);
}